// Round 20
// baseline (105.619 us; speedup 1.0000x reference)
//
#include <hip/hip_runtime.h>
#include <math.h>

#define BB 4
#define LQ 2048
#define LK 2048
#define DK 512
#define DV 512

typedef __attribute__((ext_vector_type(8))) _Float16 f16x8;
typedef __attribute__((ext_vector_type(2))) _Float16 f16x2;
typedef __attribute__((ext_vector_type(4))) float f32x4;

// ws layout (f32-element offsets)
#define WS_QW    0                 // f32[8192]
#define WS_KW    8192              // f32[8192]
#define WS_M     16384             // f32[8192]
#define WS_INV   24576             // f32[8192]
#define WS_MPACK 32768             // u32[8192*64] = 2 MB
#define WS_VF16  557056            // u16 vF[4,194,304] = 8.4 MB
#define NOUT     ((size_t)BB * LQ * DV)

// lgkmcnt-only barrier: LDS visibility without draining vmcnt (global
// stores/loads stay in flight). sched_barrier pins ds ops (rule #18).
__device__ __forceinline__ void lds_barrier() {
    __builtin_amdgcn_sched_barrier(0);
    asm volatile("s_waitcnt lgkmcnt(0)\n\ts_barrier" ::: "memory");
    __builtin_amdgcn_sched_barrier(0);
}

// ---------------------------------------------------------------------------
// A: qw/kw — one wave per row.
// ---------------------------------------------------------------------------
__global__ __launch_bounds__(256) void qkw_kernel(const float* __restrict__ q,
                                                  const float* __restrict__ k,
                                                  const float* __restrict__ w,
                                                  float* __restrict__ ws) {
    int gw   = (int)((blockIdx.x * blockDim.x + threadIdx.x) >> 6);
    int lane = threadIdx.x & 63;
    const int nq = BB * LQ;
    const float* row = (gw < nq) ? (q + (size_t)gw * DK) : (k + (size_t)(gw - nq) * DK);

    float acc = 0.f;
#pragma unroll
    for (int j = 0; j < DK; j += 256) {
        int idx = j + lane * 4;
        float4 rv = *reinterpret_cast<const float4*>(row + idx);
        float4 wv = *reinterpret_cast<const float4*>(w + idx);
        acc += rv.x * wv.x + rv.y * wv.y + rv.z * wv.z + rv.w * wv.w;
    }
#pragma unroll
    for (int off = 32; off >= 1; off >>= 1) acc += __shfl_xor(acc, off, 64);
    if (lane == 0) ws[gw] = acc;
}

// ---------------------------------------------------------------------------
// C: v -> MFMA-fragment-ordered fp16 (RTN).
// vF u16 index: (((b*32 + n16)*64 + k32)*64 + lane)*8 + j
// ---------------------------------------------------------------------------
__global__ __launch_bounds__(256) void vpack_kernel(const float* __restrict__ v,
                                                    unsigned short* __restrict__ vF) {
    __shared__ float tile[32][517];
    const int k32 = blockIdx.x;
    const int b   = blockIdx.y;
    const int k0  = k32 * 32;
    const int t   = threadIdx.x;

#pragma unroll
    for (int i = 0; i < 16; ++i) {
        int flat = i * 256 + t;
        int row  = flat >> 7;
        int c4   = flat & 127;
        float4 f = *reinterpret_cast<const float4*>(
            v + ((size_t)(b * LK + k0 + row)) * DV + c4 * 4);
        tile[row][c4 * 4 + 0] = f.x;
        tile[row][c4 * 4 + 1] = f.y;
        tile[row][c4 * 4 + 2] = f.z;
        tile[row][c4 * 4 + 3] = f.w;
    }
    __syncthreads();

    const int w = t >> 6, l = t & 63;
    const int rbase = (l >> 4) * 8;
#pragma unroll
    for (int f = 0; f < 8; ++f) {
        int n16 = w * 8 + f;
        int col = n16 * 16 + (l & 15);
        f16x8 vv;
#pragma unroll
        for (int j = 0; j < 8; ++j) vv[j] = (_Float16)tile[rbase + j][col];
        size_t u16base = (((size_t)(b * 32 + n16)) * 64 + k32) * 512;
        *reinterpret_cast<f16x8*>(vF + u16base + l * 8) = vv;
    }
}

// ---------------------------------------------------------------------------
// B1: prestat — per-row masked softmax stats (m, 1/sum) + bit-packed mask.
// One wave per row (R2-R4 verified pattern).
// ---------------------------------------------------------------------------
__global__ __launch_bounds__(256) void prestat_kernel(const int* __restrict__ mask,
                                                      float* __restrict__ ws,
                                                      unsigned int* __restrict__ mpack) {
    __shared__ float kws[LK];
    const int b = (blockIdx.x * 4) / LQ;
    const int t = threadIdx.x;

    const float4* kw4 = reinterpret_cast<const float4*>(ws + WS_KW + b * LK);
#pragma unroll
    for (int i = 0; i < 2; ++i)
        reinterpret_cast<float4*>(kws)[t + i * 256] = kw4[t + i * 256];
    __syncthreads();

    const int wave = t >> 6, lane = t & 63;
    const int rid  = blockIdx.x * 4 + wave;
    const float qwv = ws[WS_QW + rid];
    const int* mrow = mask + (size_t)rid * LK;

    float m = -INFINITY, s = 0.f;
#pragma unroll
    for (int i = 0; i < 8; ++i) {
        int e = (i * 64 + lane) * 4;
        int4  mi = *reinterpret_cast<const int4*>(mrow + e);
        float4 kv = reinterpret_cast<const float4*>(kws)[i * 64 + lane];
        float vals[4] = {kv.x, kv.y, kv.z, kv.w};
        int   msks[4] = {mi.x, mi.y, mi.z, mi.w};

        unsigned int bits = (msks[0] ? 1u : 0u) | (msks[1] ? 2u : 0u) |
                            (msks[2] ? 4u : 0u) | (msks[3] ? 8u : 0u);
        unsigned int wv = bits << ((lane & 7) * 4);
        wv |= __shfl_xor(wv, 1, 64);
        wv |= __shfl_xor(wv, 2, 64);
        wv |= __shfl_xor(wv, 4, 64);
        if ((lane & 7) == 0) mpack[(size_t)rid * 64 + i * 8 + (lane >> 3)] = wv;

#pragma unroll
        for (int j = 0; j < 4; ++j) {
            float sc = qwv - vals[j];
            sc = fmaxf(sc, 0.01f * sc);
            if (msks[j]) {
                if (sc > m) { s = s * __expf(m - sc) + 1.f; m = sc; }
                else        { s += __expf(sc - m); }
            }
        }
    }
#pragma unroll
    for (int off = 32; off >= 1; off >>= 1) {
        float mo = __shfl_xor(m, off, 64);
        float so = __shfl_xor(s, off, 64);
        float M  = fmaxf(m, mo);
        float sa = (m  == M) ? s  : s  * __expf(m  - M);
        float sb = (mo == M) ? so : so * __expf(mo - M);
        m = M; s = sa + sb;
    }
    if (lane == 0) {
        ws[WS_M   + rid] = m;
        ws[WS_INV + rid] = (s > 0.f) ? 1.f / s : 0.f;
    }
}

// ---------------------------------------------------------------------------
// B2: FUSED p-compute + attn write + single-term fp16 MFMA PV.
// R19 skeleton; staging regs replaced by in-loop exact-p computation
// (exp via mpack bits + kw LDS). ns==0 blocks write attn (once).
// Attn stores never drain: lgkm-only barrier. XCD-colocated decode.
// Block = 64 q-rows x 128 n-cols x full K. 256 thr (4 waves). 512 blocks.
// ---------------------------------------------------------------------------
__global__ __launch_bounds__(256, 2) void pv_kernel(
        const unsigned int* __restrict__ mpack,
        const float* __restrict__ ws,
        const unsigned short* __restrict__ vF,
        float* __restrict__ attn,
        float* __restrict__ out) {
    __shared__ float kw_lds[LK];             // 8 KB
    __shared__ unsigned int pH32[2][1024];   // fp16 pairs (RTN)  8 KB

    const int bid  = blockIdx.x;
    const int xcd  = bid & 7;
    const int rest = bid >> 3;             // 0..63
    const int g    = rest >> 2;            // 0..15
    const int ns   = rest & 3;
    const int qt4b = g * 8 + xcd;          // qt*4 + b, 0..127
    const int b    = qt4b & 3;
    const int qt   = qt4b >> 2;            // 0..31
    const int ksteps = LK >> 5;            // 64

    const int t = threadIdx.x;
    const int w = t >> 6, l = t & 63;

    // p-compute decode: thread t owns row (t>>6)*16 + (t&15), k-offsets
    // kb..kb+7 within each 32-chunk, kb = ((t>>4)&3)*8. Fragment-consistent:
    // staged u32s at pH32[buf][t*4..t*4+3]; reader index mf*64 + l.
    const int row_a = (t >> 6) * 16 + (t & 15);
    const int kb    = ((t >> 4) & 3) * 8;
    const int rid   = b * LQ + qt * 64 + row_a;

    for (int i = t; i < LK; i += 256)
        kw_lds[i] = ws[WS_KW + b * LK + i];

    const float qv = ws[WS_QW  + rid];
    const float mv = ws[WS_M   + rid];
    const float iv = ws[WS_INV + rid];
    const unsigned int* mrow = mpack + (size_t)rid * 64;
    float* arow = attn + (size_t)rid * LK + kb;
    const bool write_attn = (ns == 0);

    // B: wave w owns n16 = ns*8 + w*2 + nb, nb in {0,1}
    const unsigned short* bsrc[2];
#pragma unroll
    for (int nb = 0; nb < 2; ++nb)
        bsrc[nb] = vF + (((size_t)(b * 32 + ns * 8 + w * 2 + nb)) * 64) * 512
                      + (size_t)l * 8;

    // compute exact p for step s, write attn (ns==0), stage RTN fp16 to buf
    auto compute_p = [&](int s, int buf) {
        const unsigned int mw = mrow[s];
        float p[8];
#pragma unroll
        for (int i = 0; i < 8; ++i) {
            float sc = qv - kw_lds[s * 32 + kb + i];
            sc = fmaxf(sc, 0.01f * sc);
            p[i] = ((mw >> (kb + i)) & 1u) ? __expf(sc - mv) * iv : 0.f;
        }
        if (write_attn) {
            *reinterpret_cast<float4*>(arow + s * 32) =
                make_float4(p[0], p[1], p[2], p[3]);
            *reinterpret_cast<float4*>(arow + s * 32 + 4) =
                make_float4(p[4], p[5], p[6], p[7]);
        }
        unsigned int H[4];
#pragma unroll
        for (int jw = 0; jw < 4; ++jw) {
            f16x2 hv;
            hv[0] = (_Float16)p[2 * jw];
            hv[1] = (_Float16)p[2 * jw + 1];
            H[jw] = __builtin_bit_cast(unsigned int, hv);
        }
        *reinterpret_cast<uint4*>(&pH32[buf][t * 4]) = *reinterpret_cast<uint4*>(H);
    };

    // prologue: B(0) in regs; wait kw staged; p(0) -> buf0
    f16x8 bC[2], bN[2];
#pragma unroll
    for (int nb = 0; nb < 2; ++nb)
        bC[nb] = *reinterpret_cast<const f16x8*>(bsrc[nb]);

    lds_barrier();           // kw_lds visible to all waves
    compute_p(0, 0);

    f32x4 acc[4][2];
#pragma unroll
    for (int mf = 0; mf < 4; ++mf)
#pragma unroll
        for (int nb = 0; nb < 2; ++nb)
            acc[mf][nb] = (f32x4){0.f, 0.f, 0.f, 0.f};

    lds_barrier();           // p(0) staged

    for (int s = 0; s < ksteps; ++s) {
        const int buf  = s & 1;
        const int nbuf = buf ^ 1;
        const int sn   = (s + 1 < ksteps) ? s + 1 : s;

        // 1. B prefetch for next step (stays in flight across the barrier)
#pragma unroll
        for (int nb = 0; nb < 2; ++nb)
            bN[nb] = *reinterpret_cast<const f16x8*>(bsrc[nb] + (size_t)sn * 512);

        // 2. compute p(s+1) into nbuf (VALU + ds_write + fire-and-forget
        //    attn stores; overlaps other block's MFMA phase on the CU)
        compute_p(sn, nbuf);

        // 3. ds_read this step's A fragments from buf
        const f16x8* pHf = reinterpret_cast<const f16x8*>(pH32[buf]);
        f16x8 aH[4];
#pragma unroll
        for (int mf = 0; mf < 4; ++mf)
            aH[mf] = pHf[mf * 64 + l];

        // 4. MFMA cluster (8)
        __builtin_amdgcn_s_setprio(1);
#pragma unroll
        for (int nb = 0; nb < 2; ++nb)
#pragma unroll
            for (int mf = 0; mf < 4; ++mf)
                acc[mf][nb] = __builtin_amdgcn_mfma_f32_16x16x32_f16(aH[mf], bC[nb], acc[mf][nb], 0, 0, 0);
        __builtin_amdgcn_s_setprio(0);

        lds_barrier();   // lgkm-only: attn stores & B loads keep flying

#pragma unroll
        for (int nb = 0; nb < 2; ++nb) bC[nb] = bN[nb];
    }

    // ---- epilogue: col = ns*128 + (w*2+nb)*16 + (l&15),
    //      row = qt*64 + mf*16 + (l>>4)*4 + r ----
    float* obase = out + ((size_t)(b * LQ + qt * 64)) * DV
                       + ns * 128 + w * 32 + (l & 15);
#pragma unroll
    for (int mf = 0; mf < 4; ++mf)
#pragma unroll
        for (int nb = 0; nb < 2; ++nb)
#pragma unroll
            for (int r = 0; r < 4; ++r)
                obase[(size_t)(mf * 16 + (l >> 4) * 4 + r) * DV + nb * 16] = acc[mf][nb][r];
}

// ---------------------------------------------------------------------------
extern "C" void kernel_launch(void* const* d_in, const int* in_sizes, int n_in,
                              void* d_out, int out_size, void* d_ws, size_t ws_size,
                              hipStream_t stream) {
    const float* q    = (const float*)d_in[0];
    const float* k    = (const float*)d_in[1];
    const float* v    = (const float*)d_in[2];
    const int*   mask = (const int*)d_in[3];
    const float* w    = (const float*)d_in[4];

    float* out  = (float*)d_out;                       // [B, LQ, DV]
    float* attn = out + NOUT;                          // [B, LQ, LK]
    float* ws   = (float*)d_ws;

    unsigned int*   mpack = (unsigned int*)(ws + WS_MPACK);
    unsigned short* vF    = (unsigned short*)(ws + WS_VF16);

    qkw_kernel<<<4096, 256, 0, stream>>>(q, k, w, ws);
    vpack_kernel<<<dim3(64, 4), 256, 0, stream>>>(v, vF);
    prestat_kernel<<<2048, 256, 0, stream>>>(mask, ws, mpack);
    pv_kernel<<<512, 256, 0, stream>>>(mpack, ws, vF, attn, out);
}

// Round 21
// 74.799 us; speedup vs baseline: 1.4120x; 1.4120x over previous
//
#include <hip/hip_runtime.h>
#include <math.h>

#define BB 4
#define LQ 2048
#define LK 2048
#define DK 512
#define DV 512

typedef __attribute__((ext_vector_type(8))) _Float16 f16x8;
typedef __attribute__((ext_vector_type(2))) _Float16 f16x2;
typedef __attribute__((ext_vector_type(4))) float f32x4;

// ws layout (f32-element offsets)
#define WS_QW    0                 // f32[8192]
#define WS_KW    8192              // f32[8192]
#define WS_M     16384             // f32[8192]
#define WS_INV   24576             // f32[8192]
#define WS_VF16  32768             // u16 vF[4,194,304] = 8.4 MB
#define NOUT     ((size_t)BB * LQ * DV)

// lgkmcnt-only barrier: LDS visibility without draining vmcnt.
__device__ __forceinline__ void lds_barrier() {
    __builtin_amdgcn_sched_barrier(0);
    asm volatile("s_waitcnt lgkmcnt(0)\n\ts_barrier" ::: "memory");
    __builtin_amdgcn_sched_barrier(0);
}

// ---------------------------------------------------------------------------
// A: qw/kw — one wave per row.
// ---------------------------------------------------------------------------
__global__ __launch_bounds__(256) void qkw_kernel(const float* __restrict__ q,
                                                  const float* __restrict__ k,
                                                  const float* __restrict__ w,
                                                  float* __restrict__ ws) {
    int gw   = (int)((blockIdx.x * blockDim.x + threadIdx.x) >> 6);
    int lane = threadIdx.x & 63;
    const int nq = BB * LQ;
    const float* row = (gw < nq) ? (q + (size_t)gw * DK) : (k + (size_t)(gw - nq) * DK);

    float acc = 0.f;
#pragma unroll
    for (int j = 0; j < DK; j += 256) {
        int idx = j + lane * 4;
        float4 rv = *reinterpret_cast<const float4*>(row + idx);
        float4 wv = *reinterpret_cast<const float4*>(w + idx);
        acc += rv.x * wv.x + rv.y * wv.y + rv.z * wv.z + rv.w * wv.w;
    }
#pragma unroll
    for (int off = 32; off >= 1; off >>= 1) acc += __shfl_xor(acc, off, 64);
    if (lane == 0) ws[gw] = acc;
}

// ---------------------------------------------------------------------------
// C: v -> MFMA-fragment-ordered fp16 (RTN).
// vF u16 index: (((b*32 + n16)*64 + k32)*64 + lane)*8 + j
// ---------------------------------------------------------------------------
__global__ __launch_bounds__(256) void vpack_kernel(const float* __restrict__ v,
                                                    unsigned short* __restrict__ vF) {
    __shared__ float tile[32][517];
    const int k32 = blockIdx.x;
    const int b   = blockIdx.y;
    const int k0  = k32 * 32;
    const int t   = threadIdx.x;

#pragma unroll
    for (int i = 0; i < 16; ++i) {
        int flat = i * 256 + t;
        int row  = flat >> 7;
        int c4   = flat & 127;
        float4 f = *reinterpret_cast<const float4*>(
            v + ((size_t)(b * LK + k0 + row)) * DV + c4 * 4);
        tile[row][c4 * 4 + 0] = f.x;
        tile[row][c4 * 4 + 1] = f.y;
        tile[row][c4 * 4 + 2] = f.z;
        tile[row][c4 * 4 + 3] = f.w;
    }
    __syncthreads();

    const int w = t >> 6, l = t & 63;
    const int rbase = (l >> 4) * 8;
#pragma unroll
    for (int f = 0; f < 8; ++f) {
        int n16 = w * 8 + f;
        int col = n16 * 16 + (l & 15);
        f16x8 vv;
#pragma unroll
        for (int j = 0; j < 8; ++j) vv[j] = (_Float16)tile[rbase + j][col];
        size_t u16base = (((size_t)(b * 32 + n16)) * 64 + k32) * 512;
        *reinterpret_cast<f16x8*>(vF + u16base + l * 8) = vv;
    }
}

// ---------------------------------------------------------------------------
// B1: per-row masked softmax stats + full attn row write (exact f32 p).
// ---------------------------------------------------------------------------
__global__ __launch_bounds__(256) void rowstat_kernel(const int* __restrict__ mask,
                                                      float* __restrict__ ws,
                                                      float* __restrict__ attn) {
    __shared__ float kws[LK];
    const int b = (blockIdx.x * 4) / LQ;
    const int t = threadIdx.x;

    const float4* kw4 = reinterpret_cast<const float4*>(ws + WS_KW + b * LK);
#pragma unroll
    for (int i = 0; i < 2; ++i)
        reinterpret_cast<float4*>(kws)[t + i * 256] = kw4[t + i * 256];
    __syncthreads();

    const int wave = t >> 6, lane = t & 63;
    const int rid  = blockIdx.x * 4 + wave;
    const float qwv = ws[WS_QW + rid];
    const int* mrow = mask + (size_t)rid * LK;

    float m = -INFINITY, s = 0.f;
    unsigned int mybits = 0;
#pragma unroll
    for (int i = 0; i < 8; ++i) {
        int e = (i * 64 + lane) * 4;
        int4  mi = *reinterpret_cast<const int4*>(mrow + e);
        float4 kv = reinterpret_cast<const float4*>(kws)[i * 64 + lane];
        float vals[4] = {kv.x, kv.y, kv.z, kv.w};
        int   msks[4] = {mi.x, mi.y, mi.z, mi.w};

        unsigned int bits = (msks[0] ? 1u : 0u) | (msks[1] ? 2u : 0u) |
                            (msks[2] ? 4u : 0u) | (msks[3] ? 8u : 0u);
        mybits |= bits << (i * 4);

#pragma unroll
        for (int j = 0; j < 4; ++j) {
            float sc = qwv - vals[j];
            sc = fmaxf(sc, 0.01f * sc);
            if (msks[j]) {
                if (sc > m) { s = s * __expf(m - sc) + 1.f; m = sc; }
                else        { s += __expf(sc - m); }
            }
        }
    }
#pragma unroll
    for (int off = 32; off >= 1; off >>= 1) {
        float mo = __shfl_xor(m, off, 64);
        float so = __shfl_xor(s, off, 64);
        float M  = fmaxf(m, mo);
        float sa = (m  == M) ? s  : s  * __expf(m  - M);
        float sb = (mo == M) ? so : so * __expf(mo - M);
        m = M; s = sa + sb;
    }
    const float inv = (s > 0.f) ? 1.f / s : 0.f;
    if (lane == 0) {
        ws[WS_M   + rid] = m;
        ws[WS_INV + rid] = inv;
    }

    float* arow = attn + (size_t)rid * LK;
#pragma unroll
    for (int i = 0; i < 8; ++i) {
        float4 kv = reinterpret_cast<const float4*>(kws)[i * 64 + lane];
        float vals[4] = {kv.x, kv.y, kv.z, kv.w};
        unsigned int bits = (mybits >> (i * 4)) & 0xFu;
        float p[4];
#pragma unroll
        for (int j = 0; j < 4; ++j) {
            float sc = qwv - vals[j];
            sc = fmaxf(sc, 0.01f * sc);
            p[j] = (bits & (1u << j)) ? __expf(sc - m) * inv : 0.f;
        }
        *reinterpret_cast<float4*>(arow + (i * 64 + lane) * 4) =
            make_float4(p[0], p[1], p[2], p[3]);
    }
}

// ---------------------------------------------------------------------------
// B2: PV matmul, single-term RTN fp16 (R19 math), HIGH-OCCUPANCY geometry:
// block = 32 q-rows x 256 n-cols x full K, 512 thr (8 waves), wave = 32x32.
// 512 blocks = 2 blocks/CU = 16 waves/CU = 4 waves/SIMD (2x R19's TLP);
// A-duplication drops 4x -> 2x. Staging: waves 0-1 only (t<128), exact R19
// decode. XCD-colocated: both col-halves of a row-unit share an XCD.
// ---------------------------------------------------------------------------
__global__ __launch_bounds__(512, 2) void pv_kernel(
        const float* __restrict__ attn,
        const unsigned short* __restrict__ vF,
        float* __restrict__ out) {
    __shared__ unsigned int pH32[2][512];   // fp16 pairs (RTN), 4 KB

    const int bid  = blockIdx.x;
    const int xcd  = bid & 7;
    const int rest = bid >> 3;             // 0..63
    const int g    = rest >> 1;            // 0..31
    const int ns   = rest & 1;             // col half
    const int u32i = g * 8 + xcd;          // row-unit (32 rows), 0..255
    const int b    = u32i >> 6;
    const int ksteps = LK >> 5;            // 64

    const int t = threadIdx.x;
    const int w = t >> 6, l = t & 63;
    const bool stager = (t < 128);         // waves 0-1 stage A

    // A staging decode (t<128): row = (t>>6)*16 + (t&15)  [0..31],
    // k in [kb, kb+8), kb = ((t>>4)&3)*8. Writes uint4 at u32[4t].
    const int row_a = (t >> 6) * 16 + (t & 15);
    const int kb    = ((t >> 4) & 3) * 8;
    const int rid   = u32i * 32 + row_a;
    const float* arow = attn + (size_t)rid * LK + kb;

    // B: wave w owns n16 = ns*16 + w*2 + nb, nb in {0,1}
    const unsigned short* bsrc[2];
#pragma unroll
    for (int nb = 0; nb < 2; ++nb)
        bsrc[nb] = vF + (((size_t)(b * 32 + ns * 16 + w * 2 + nb)) * 64) * 512
                      + (size_t)l * 8;

    // stage 8 floats -> RTN fp16 pairs at u32[4t..4t+4)
    auto stage = [&](const float4& x, const float4& y, int buf) {
        unsigned int H[4];
        float f[8] = {x.x, x.y, x.z, x.w, y.x, y.y, y.z, y.w};
#pragma unroll
        for (int jw = 0; jw < 4; ++jw) {
            f16x2 hv;
            hv[0] = (_Float16)f[2 * jw];
            hv[1] = (_Float16)f[2 * jw + 1];
            H[jw] = __builtin_bit_cast(unsigned int, hv);
        }
        *reinterpret_cast<uint4*>(&pH32[buf][t * 4]) = *reinterpret_cast<uint4*>(H);
    };

    // prologue
    f16x8 bC[2], bN[2];
#pragma unroll
    for (int nb = 0; nb < 2; ++nb)
        bC[nb] = *reinterpret_cast<const f16x8*>(bsrc[nb]);

    float4 aCx = {0, 0, 0, 0}, aCy = {0, 0, 0, 0};
    if (stager) {
        float4 x = *reinterpret_cast<const float4*>(arow);
        float4 y = *reinterpret_cast<const float4*>(arow + 4);
        stage(x, y, 0);
        aCx = *reinterpret_cast<const float4*>(arow + 32);
        aCy = *reinterpret_cast<const float4*>(arow + 36);
    }

    f32x4 acc[2][2];
#pragma unroll
    for (int mf = 0; mf < 2; ++mf)
#pragma unroll
        for (int nb = 0; nb < 2; ++nb)
            acc[mf][nb] = (f32x4){0.f, 0.f, 0.f, 0.f};

    lds_barrier();

    for (int s = 0; s < ksteps; ++s) {
        const int buf  = s & 1;
        const int nbuf = buf ^ 1;
        const int sn   = (s + 1 < ksteps) ? s + 1 : s;
        const int sn2  = (s + 2 < ksteps) ? s + 2 : s;

        // 1. global prefetches (span the barrier)
#pragma unroll
        for (int nb = 0; nb < 2; ++nb)
            bN[nb] = *reinterpret_cast<const f16x8*>(bsrc[nb] + (size_t)sn * 512);
        float4 aNx, aNy;
        if (stager) {
            aNx = *reinterpret_cast<const float4*>(arow + sn2 * 32);
            aNy = *reinterpret_cast<const float4*>(arow + sn2 * 32 + 4);
        }

        // 2. stage A(s+1) into nbuf (waves 0-1)
        if (stager) stage(aCx, aCy, nbuf);

        // 3. ds_read this step's A fragments from buf
        const f16x8* pHf = reinterpret_cast<const f16x8*>(pH32[buf]);
        f16x8 aH[2];
#pragma unroll
        for (int mf = 0; mf < 2; ++mf)
            aH[mf] = pHf[mf * 64 + l];

        // 4. MFMA cluster (4)
        __builtin_amdgcn_s_setprio(1);
#pragma unroll
        for (int nb = 0; nb < 2; ++nb)
#pragma unroll
            for (int mf = 0; mf < 2; ++mf)
                acc[mf][nb] = __builtin_amdgcn_mfma_f32_16x16x32_f16(aH[mf], bC[nb], acc[mf][nb], 0, 0, 0);
        __builtin_amdgcn_s_setprio(0);

        lds_barrier();   // lgkm-only: global loads keep flying

#pragma unroll
        for (int nb = 0; nb < 2; ++nb) bC[nb] = bN[nb];
        if (stager) { aCx = aNx; aCy = aNy; }
    }

    // ---- epilogue: col = ns*256 + (w*2+nb)*16 + (l&15),
    //      row = u32i*32 + mf*16 + (l>>4)*4 + r ----
    float* obase = out + ((size_t)u32i * 32) * DV
                       + ns * 256 + w * 32 + (l & 15);
#pragma unroll
    for (int mf = 0; mf < 2; ++mf)
#pragma unroll
        for (int nb = 0; nb < 2; ++nb)
#pragma unroll
            for (int r = 0; r < 4; ++r)
                obase[(size_t)(mf * 16 + (l >> 4) * 4 + r) * DV + nb * 16] = acc[mf][nb][r];
}

// ---------------------------------------------------------------------------
extern "C" void kernel_launch(void* const* d_in, const int* in_sizes, int n_in,
                              void* d_out, int out_size, void* d_ws, size_t ws_size,
                              hipStream_t stream) {
    const float* q    = (const float*)d_in[0];
    const float* k    = (const float*)d_in[1];
    const float* v    = (const float*)d_in[2];
    const int*   mask = (const int*)d_in[3];
    const float* w    = (const float*)d_in[4];

    float* out  = (float*)d_out;                       // [B, LQ, DV]
    float* attn = out + NOUT;                          // [B, LQ, LK]
    float* ws   = (float*)d_ws;

    unsigned short* vF = (unsigned short*)(ws + WS_VF16);

    qkw_kernel<<<4096, 256, 0, stream>>>(q, k, w, ws);
    vpack_kernel<<<dim3(64, 4), 256, 0, stream>>>(v, vF);
    rowstat_kernel<<<2048, 256, 0, stream>>>(mask, ws, attn);
    pv_kernel<<<512, 512, 0, stream>>>(attn, vF, out);
}